// Round 3
// baseline (1043.515 us; speedup 1.0000x reference)
//
#include <hip/hip_runtime.h>
#include <math.h>

#define NN 50000
#define NE 600000
#define DD 128
#define NL 4
#define NG 512
#define NT 10
#define EPSF 1e-5f

typedef __bf16 bf16x8 __attribute__((ext_vector_type(8)));
typedef float f32x4 __attribute__((ext_vector_type(4)));

__device__ __forceinline__ unsigned short f2bf(float x) {
    union { float f; unsigned u; } v; v.f = x;
    unsigned r = v.u + 0x7FFFu + ((v.u >> 16) & 1u);
    return (unsigned short)(r >> 16);
}
__device__ __forceinline__ unsigned pack_bf2(float a, float b) {
    return (unsigned)f2bf(a) | ((unsigned)f2bf(b) << 16);
}
__device__ __forceinline__ float bf_lo(unsigned v) {
    union { unsigned u; float f; } w; w.u = (v & 0xFFFFu) << 16; return w.f;
}
__device__ __forceinline__ float bf_hi(unsigned v) {
    union { unsigned u; float f; } w; w.u = v & 0xFFFF0000u; return w.f;
}

// ---------------- CSR build ----------------
__global__ void k_count(const int* __restrict__ dst, int* __restrict__ deg,
                        float* __restrict__ dsum, int E) {
    int e = blockIdx.x * blockDim.x + threadIdx.x;
    if (e == 0) *dsum = 0.f;                 // consumed by k_delta (later kernel)
    if (e < E) atomicAdd(&deg[dst[e]], 1);
}

// parallel scan: 49 blocks x 256 thr, 4 elems/thread (1024/block)
__global__ void k_scan_part(const int* __restrict__ deg, int* __restrict__ part, int n) {
    __shared__ int sm[256];
    int b = blockIdx.x, t = threadIdx.x;
    int base = b * 1024 + t * 4;
    int s = 0;
    #pragma unroll
    for (int j = 0; j < 4; j++) if (base + j < n) s += deg[base + j];
    sm[t] = s;
    __syncthreads();
    for (int off = 128; off > 0; off >>= 1) {
        if (t < off) sm[t] += sm[t + off];
        __syncthreads();
    }
    if (t == 0) part[b] = sm[0];
}

__global__ void k_scan_top(const int* __restrict__ part, int* __restrict__ offs,
                           int* __restrict__ row_ptr, int nb, int n) {
    if (threadIdx.x == 0) {
        int acc = 0;
        for (int i = 0; i < nb; i++) { offs[i] = acc; acc += part[i]; }
        row_ptr[n] = acc;
    }
}

__global__ void k_scan_apply(const int* __restrict__ deg, const int* __restrict__ offs,
                             int* __restrict__ row_ptr, int* __restrict__ cursor, int n) {
    __shared__ int sm[256];
    int b = blockIdx.x, t = threadIdx.x;
    int base = b * 1024 + t * 4;
    int v[4]; int s = 0;
    #pragma unroll
    for (int j = 0; j < 4; j++) { v[j] = (base + j < n) ? deg[base + j] : 0; s += v[j]; }
    sm[t] = s;
    __syncthreads();
    for (int off = 1; off < 256; off <<= 1) {
        int y = (t >= off) ? sm[t - off] : 0;
        __syncthreads();
        sm[t] += y;
        __syncthreads();
    }
    int run = offs[b] + sm[t] - s;
    #pragma unroll
    for (int j = 0; j < 4; j++) {
        if (base + j < n) { row_ptr[base + j] = run; cursor[base + j] = run; run += v[j]; }
    }
}

__global__ void k_fill(const int* __restrict__ src, const int* __restrict__ dst,
                       int* __restrict__ cursor, int* __restrict__ csr_src, int E) {
    int e = blockIdx.x * blockDim.x + threadIdx.x;
    if (e < E) {
        int d = dst[e];
        int pos = atomicAdd(&cursor[d], 1);
        csr_src[pos] = src[e];
    }
}

// ---------------- degree scalars ----------------
__global__ void k_delta(const int* __restrict__ deg, float* __restrict__ dsum, int n) {
    int i = blockIdx.x * blockDim.x + threadIdx.x;
    float v = (i < n) ? log1pf((float)deg[i]) : 0.f;
    #pragma unroll
    for (int off = 32; off > 0; off >>= 1) v += __shfl_down(v, off);
    if ((threadIdx.x & 63) == 0) atomicAdd(dsum, v);
}

__global__ void k_scalars(const int* __restrict__ deg, const float* __restrict__ dsum,
                          float* __restrict__ inv_d, float* __restrict__ amp,
                          float* __restrict__ att, int n) {
    int i = blockIdx.x * blockDim.x + threadIdx.x;
    if (i >= n) return;
    float delta = *dsum / (float)n;
    float d = fmaxf((float)deg[i], 1.f);
    float ld = log1pf(d);
    inv_d[i] = 1.f / d;
    amp[i] = ld / delta;
    att[i] = delta / ld;
}

// ---------------- node embedding (fp32 h + bf16 mirror) ----------------
__global__ void k_emb(const float* __restrict__ x, const float* __restrict__ W,
                      const float* __restrict__ b, float* __restrict__ h,
                      unsigned* __restrict__ hb2, int total2) {
    int i = blockIdx.x * blockDim.x + threadIdx.x;
    if (i >= total2) return;
    int node = i >> 6, c = (i & 63) * 2;
    float x0 = x[node * 3 + 0], x1 = x[node * 3 + 1], x2 = x[node * 3 + 2];
    float v0 = x0 * W[c] + x1 * W[DD + c] + x2 * W[2 * DD + c] + b[c];
    float v1 = x0 * W[c + 1] + x1 * W[DD + c + 1] + x2 * W[2 * DD + c + 1] + b[c + 1];
    ((float2*)h)[i] = make_float2(v0, v1);
    hb2[i] = pack_bf2(v0, v1);
}

// ---------------- weight convert: conv_W [L,1536,128] f32 -> Bt [L][3][128][512] bf16 ----
__global__ void k_wconv(const float* __restrict__ W, unsigned short* __restrict__ Bt, int total) {
    int o = blockIdx.x * blockDim.x + threadIdx.x;
    if (o >= total) return;
    int l = o / 196608;
    int r = o % 196608;
    int j = r >> 16;
    int r2 = r & 65535;
    int n = r2 >> 9;
    int k = r2 & 511;
    Bt[o] = f2bf(W[(size_t)l * 196608 + (size_t)(j * 512 + k) * 128 + n]);
}

// ---------------- PNA aggregation (4 nodes/block, wave per node) ----------------
__global__ void k_agg(const unsigned* __restrict__ hb2, const int* __restrict__ row_ptr,
                      const int* __restrict__ csr_src, const float* __restrict__ inv_d,
                      unsigned* __restrict__ aggs_u, float* __restrict__ bn_zero) {
    int tid = threadIdx.x;
    if (blockIdx.x == 0) bn_zero[tid] = 0.f;   // zero bn_sum[128]+bn_sq[128] for next gemm
    int node = blockIdx.x * 4 + (tid >> 6);
    int t = tid & 63;
    int beg = row_ptr[node], end = row_ptr[node + 1];
    float s1a = 0.f, s1b = 0.f, s2a = 0.f, s2b = 0.f;
    float mna = INFINITY, mnb = INFINITY, mxa = -INFINITY, mxb = -INFINITY;
    for (int e = beg; e < end; e++) {
        int s = csr_src[e];
        unsigned v = hb2[(size_t)s * 64 + t];
        float a = bf_lo(v), b = bf_hi(v);
        s1a += a; s2a += a * a; mna = fminf(mna, a); mxa = fmaxf(mxa, a);
        s1b += b; s2b += b * b; mnb = fminf(mnb, b); mxb = fmaxf(mxb, b);
    }
    float id = inv_d[node];
    float meana = s1a * id, meanb = s1b * id;
    float sda = sqrtf(fmaxf(s2a * id - meana * meana, 0.f) + EPSF);
    float sdb = sqrtf(fmaxf(s2b * id - meanb * meanb, 0.f) + EPSF);
    if (beg == end) { mna = 0.f; mxa = 0.f; mnb = 0.f; mxb = 0.f; }
    unsigned* outr = aggs_u + (size_t)node * 256;
    outr[t]       = pack_bf2(meana, meanb);
    outr[64 + t]  = pack_bf2(mna, mnb);
    outr[128 + t] = pack_bf2(mxa, mxb);
    outr[192 + t] = pack_bf2(sda, sdb);
}

// ---------------- MFMA GEMM v3: register-prefetch pipeline ----------------
// A = aggs bf16 [N,512]; Bt = [3][128][512] bf16 (n-major, k contiguous).
// out[r,c] = sum_k A[r,k]*(B0 + amp[r]*B1 + att[r]*B2)[k,c] + bias[c]
// Block: 256 thr (4 waves), tile 64 rows x 128 cols; wave w owns cols [32w,32w+32).
// LDS row stride 40 shorts (80 B): 16B-aligned b128, 2-way-max bank aliasing (free).
__global__ __launch_bounds__(256, 2) void k_gemm_mfma(
    const unsigned short* __restrict__ A, const unsigned short* __restrict__ Bt,
    const float* __restrict__ bias, const float* __restrict__ amp,
    const float* __restrict__ att, float* __restrict__ outp,
    float* __restrict__ bn_sum, float* __restrict__ bn_sq, int n) {
    __shared__ unsigned short As[64 * 40];
    __shared__ unsigned short Bs[3 * 128 * 40];
    int tid = threadIdx.x;
    int w = tid >> 6, lane = tid & 63;
    int quad = lane >> 4, l16 = lane & 15;
    int row0 = blockIdx.x * 64;

    f32x4 acc[4][2][3];
    #pragma unroll
    for (int rt = 0; rt < 4; rt++)
        #pragma unroll
        for (int ct = 0; ct < 2; ct++)
            #pragma unroll
            for (int j = 0; j < 3; j++) acc[rt][ct][j] = (f32x4)(0.f);

    // staging addresses
    const unsigned short* pA = A + (size_t)(row0 + (tid >> 2)) * 512 + (tid & 3) * 8;
    int a_lds = (tid >> 2) * 40 + (tid & 3) * 8;
    const unsigned short* pB[6];
    int b_lds[6];
    #pragma unroll
    for (int i = 0; i < 6; i++) {
        int c = i * 256 + tid;
        int j = c >> 9, rem = c & 511, nn = rem >> 2, kc = rem & 3;
        pB[i] = Bt + (size_t)(j * 128 + nn) * 512 + kc * 8;
        b_lds[i] = (j * 128 + nn) * 40 + kc * 8;
    }
    int a_off[4];
    #pragma unroll
    for (int rt = 0; rt < 4; rt++) a_off[rt] = (rt * 16 + l16) * 40 + quad * 8;
    int b_off[2][3];
    #pragma unroll
    for (int ct = 0; ct < 2; ct++)
        #pragma unroll
        for (int j = 0; j < 3; j++)
            b_off[ct][j] = (j * 128 + w * 32 + ct * 16 + l16) * 40 + quad * 8;

    // preload tile 0 into registers
    uint4 ra = *(const uint4*)pA;
    uint4 rb[6];
    #pragma unroll
    for (int i = 0; i < 6; i++) rb[i] = *(const uint4*)pB[i];

    for (int it = 0; it < 16; it++) {
        __syncthreads();
        *(uint4*)&As[a_lds] = ra;
        #pragma unroll
        for (int i = 0; i < 6; i++) *(uint4*)&Bs[b_lds[i]] = rb[i];
        __syncthreads();
        if (it < 15) {                      // prefetch next tile (hidden by MFMAs)
            int ko = (it + 1) * 32;
            ra = *(const uint4*)(pA + ko);
            #pragma unroll
            for (int i = 0; i < 6; i++) rb[i] = *(const uint4*)(pB[i] + ko);
        }
        bf16x8 af[4];
        #pragma unroll
        for (int rt = 0; rt < 4; rt++) af[rt] = *(const bf16x8*)&As[a_off[rt]];
        #pragma unroll
        for (int ct = 0; ct < 2; ct++) {
            #pragma unroll
            for (int j = 0; j < 3; j++) {
                bf16x8 bf = *(const bf16x8*)&Bs[b_off[ct][j]];
                #pragma unroll
                for (int rt = 0; rt < 4; rt++)
                    acc[rt][ct][j] = __builtin_amdgcn_mfma_f32_16x16x32_bf16(
                        af[rt], bf, acc[rt][ct][j], 0, 0, 0);
            }
        }
    }

    // epilogue: combine j via amp/att, bias, write, BN partials
    float psum[2] = {0.f, 0.f}, psq[2] = {0.f, 0.f};
    #pragma unroll
    for (int rt = 0; rt < 4; rt++) {
        #pragma unroll
        for (int reg = 0; reg < 4; reg++) {
            int row = row0 + rt * 16 + quad * 4 + reg;
            if (row < n) {
                float am = amp[row], at = att[row];
                #pragma unroll
                for (int ct = 0; ct < 2; ct++) {
                    int col = w * 32 + ct * 16 + l16;
                    float v = acc[rt][ct][0][reg] + am * acc[rt][ct][1][reg]
                            + at * acc[rt][ct][2][reg] + bias[col];
                    outp[(size_t)row * DD + col] = v;
                    psum[ct] += v;
                    psq[ct] += v * v;
                }
            }
        }
    }
    #pragma unroll
    for (int ct = 0; ct < 2; ct++) {
        psum[ct] += __shfl_xor(psum[ct], 16, 64);
        psum[ct] += __shfl_xor(psum[ct], 32, 64);
        psq[ct]  += __shfl_xor(psq[ct], 16, 64);
        psq[ct]  += __shfl_xor(psq[ct], 32, 64);
    }
    if (quad == 0) {
        #pragma unroll
        for (int ct = 0; ct < 2; ct++) {
            int col = w * 32 + ct * 16 + l16;
            atomicAdd(&bn_sum[col], psum[ct]);
            atomicAdd(&bn_sq[col], psq[ct]);
        }
    }
}

// ---------------- BN stats ----------------
__global__ void k_bnstats(const float* __restrict__ bn_sum, const float* __restrict__ bn_sq,
                          const float* __restrict__ gamma, const float* __restrict__ beta,
                          float* __restrict__ scale, float* __restrict__ shift, int n) {
    int c = threadIdx.x;
    float mu = bn_sum[c] / (float)n;
    float var = bn_sq[c] / (float)n - mu * mu;
    float sc = rsqrtf(var + EPSF) * gamma[c];
    scale[c] = sc;
    shift[c] = beta[c] - mu * sc;
}

// ---------------- BN apply + relu + residual (updates h fp32 + bf16 mirror) --------
__global__ void k_bnapply(const float* __restrict__ outp, const float* __restrict__ scale,
                          const float* __restrict__ shift, float* __restrict__ h,
                          unsigned* __restrict__ hb2, int total2) {
    int i = blockIdx.x * blockDim.x + threadIdx.x;
    if (i >= total2) return;
    int c = (i & 63) * 2;
    float2 o = ((const float2*)outp)[i];
    float v0 = fmaxf(o.x * scale[c] + shift[c], 0.f);
    float v1 = fmaxf(o.y * scale[c + 1] + shift[c + 1], 0.f);
    float2 hh = ((float2*)h)[i];
    hh.x += v0; hh.y += v1;
    ((float2*)h)[i] = hh;
    hb2[i] = pack_bf2(hh.x, hh.y);
}

// ---------------- pool + MLP ----------------
__global__ void k_pool_mlp(const float* __restrict__ h, const int* __restrict__ batch,
                           const float* __restrict__ W1, const float* __restrict__ b1,
                           const float* __restrict__ W2, const float* __restrict__ b2,
                           const float* __restrict__ W3, const float* __restrict__ b3,
                           float* __restrict__ out, int n) {
    __shared__ float gvec[128];
    __shared__ float h1[64];
    __shared__ float h2[32];
    __shared__ int srange[2];
    int g = blockIdx.x;
    int t = threadIdx.x;
    if (t < 2) {
        int target = g + t;
        int lo = 0, hi = n;
        while (lo < hi) {
            int mid = (lo + hi) >> 1;
            if (batch[mid] < target) lo = mid + 1; else hi = mid;
        }
        srange[t] = lo;
    }
    __syncthreads();
    int s = srange[0], e = srange[1];
    float acc = 0.f;
    for (int i = s; i < e; i++) acc += h[(size_t)i * DD + t];
    float cnt = fmaxf((float)(e - s), 1.f);
    gvec[t] = acc / cnt;
    __syncthreads();
    if (t < 64) {
        float a = b1[t];
        for (int k = 0; k < 128; k++) a += gvec[k] * W1[k * 64 + t];
        h1[t] = fmaxf(a, 0.f);
    }
    __syncthreads();
    if (t < 32) {
        float a = b2[t];
        for (int k = 0; k < 64; k++) a += h1[k] * W2[k * 32 + t];
        h2[t] = fmaxf(a, 0.f);
    }
    __syncthreads();
    if (t < 10) {
        float a = b3[t];
        for (int k = 0; k < 32; k++) a += h2[k] * W3[k * 10 + t];
        out[g * NT + t] = a;
    }
}

extern "C" void kernel_launch(void* const* d_in, const int* in_sizes, int n_in,
                              void* d_out, int out_size, void* d_ws, size_t ws_size,
                              hipStream_t stream) {
    const float* x      = (const float*)d_in[0];
    const int*   eidx   = (const int*)d_in[1];
    const int*   batch  = (const int*)d_in[2];
    const float* emb_W  = (const float*)d_in[3];
    const float* emb_b  = (const float*)d_in[4];
    const float* conv_W = (const float*)d_in[5];
    const float* conv_b = (const float*)d_in[6];
    const float* bn_g   = (const float*)d_in[7];
    const float* bn_b   = (const float*)d_in[8];
    const float* W1 = (const float*)d_in[9];
    const float* b1 = (const float*)d_in[10];
    const float* W2 = (const float*)d_in[11];
    const float* b2 = (const float*)d_in[12];
    const float* W3 = (const float*)d_in[13];
    const float* b3 = (const float*)d_in[14];
    float* out = (float*)d_out;

    const int* src = eidx;
    const int* dst = eidx + NE;

    char* p = (char*)d_ws;
    auto carve = [&](size_t bytes) {
        void* r = (void*)p;
        p += (bytes + 255) & ~(size_t)255;
        return r;
    };
    int* deg      = (int*)carve(NN * 4);
    int* row_ptr  = (int*)carve((NN + 1) * 4);
    int* cursor   = (int*)carve(NN * 4);
    int* csr_src  = (int*)carve(NE * 4);
    int* part     = (int*)carve(64 * 4);
    int* offs     = (int*)carve(64 * 4);
    float* inv_d  = (float*)carve(NN * 4);
    float* amp    = (float*)carve(NN * 4);
    float* att    = (float*)carve(NN * 4);
    float* dsum   = (float*)carve(4);
    float* bn_sum = (float*)carve(DD * 4);
    float* bn_sq  = (float*)carve(DD * 4);
    float* scale  = (float*)carve(DD * 4);
    float* shift  = (float*)carve(DD * 4);
    float* h      = (float*)carve((size_t)NN * DD * 4);
    unsigned* hb2 = (unsigned*)carve((size_t)NN * 64 * 4);
    unsigned* aggs_u = (unsigned*)carve((size_t)NN * 256 * 4);   // bf16 [N,512]
    float* outp   = (float*)carve((size_t)NN * DD * 4);          // must follow aggs (OOB pad)
    unsigned short* Bt = (unsigned short*)carve((size_t)NL * 3 * 128 * 512 * 2);

    hipMemsetAsync(deg, 0, NN * 4, stream);

    const int NSB = (NN + 1023) / 1024;   // 49 scan blocks
    k_count<<<(NE + 255) / 256, 256, 0, stream>>>(dst, deg, dsum, NE);
    k_scan_part<<<NSB, 256, 0, stream>>>(deg, part, NN);
    k_scan_top<<<1, 64, 0, stream>>>(part, offs, row_ptr, NSB, NN);
    k_scan_apply<<<NSB, 256, 0, stream>>>(deg, offs, row_ptr, cursor, NN);
    k_fill<<<(NE + 255) / 256, 256, 0, stream>>>(src, dst, cursor, csr_src, NE);
    k_delta<<<(NN + 255) / 256, 256, 0, stream>>>(deg, dsum, NN);
    k_scalars<<<(NN + 255) / 256, 256, 0, stream>>>(deg, dsum, inv_d, amp, att, NN);
    k_emb<<<(NN * 64 + 255) / 256, 256, 0, stream>>>(x, emb_W, emb_b, h, hb2, NN * 64);
    k_wconv<<<(NL * 196608 + 255) / 256, 256, 0, stream>>>(conv_W, Bt, NL * 196608);

    int gemm_blocks = (NN + 63) / 64;
    for (int l = 0; l < NL; l++) {
        k_agg<<<(NN + 3) / 4, 256, 0, stream>>>(hb2, row_ptr, csr_src, inv_d, aggs_u, bn_sum);
        k_gemm_mfma<<<gemm_blocks, 256, 0, stream>>>(
            (const unsigned short*)aggs_u, Bt + (size_t)l * 3 * 128 * 512,
            conv_b + l * DD, amp, att, outp, bn_sum, bn_sq, NN);
        k_bnstats<<<1, DD, 0, stream>>>(bn_sum, bn_sq, bn_g + l * DD, bn_b + l * DD,
                                        scale, shift, NN);
        k_bnapply<<<(NN * 64 + 255) / 256, 256, 0, stream>>>(outp, scale, shift, h, hb2, NN * 64);
    }

    k_pool_mlp<<<NG, 128, 0, stream>>>(h, batch, W1, b1, W2, b2, W3, b3, out, NN);
}

// Round 4
// 689.341 us; speedup vs baseline: 1.5138x; 1.5138x over previous
//
#include <hip/hip_runtime.h>
#include <math.h>

#define NN 50000
#define NE 600000
#define DD 128
#define NL 4
#define NG 512
#define NT 10
#define EPSF 1e-5f

typedef __bf16 bf16x8 __attribute__((ext_vector_type(8)));
typedef float f32x4 __attribute__((ext_vector_type(4)));

__device__ __forceinline__ unsigned short f2bf(float x) {
    union { float f; unsigned u; } v; v.f = x;
    unsigned r = v.u + 0x7FFFu + ((v.u >> 16) & 1u);
    return (unsigned short)(r >> 16);
}
__device__ __forceinline__ unsigned pack_bf2(float a, float b) {
    return (unsigned)f2bf(a) | ((unsigned)f2bf(b) << 16);
}
__device__ __forceinline__ float bf_lo(unsigned v) {
    union { unsigned u; float f; } w; w.u = (v & 0xFFFFu) << 16; return w.f;
}
__device__ __forceinline__ float bf_hi(unsigned v) {
    union { unsigned u; float f; } w; w.u = v & 0xFFFF0000u; return w.f;
}
__device__ __forceinline__ void ld16(const void* g, void* l) {
    __builtin_amdgcn_global_load_lds(
        (const __attribute__((address_space(1))) unsigned int*)g,
        (__attribute__((address_space(3))) unsigned int*)l, 16, 0, 0);
}

// ---------------- CSR build ----------------
__global__ void k_count(const int* __restrict__ dst, int* __restrict__ deg,
                        float* __restrict__ dsum, int E) {
    int e = blockIdx.x * blockDim.x + threadIdx.x;
    if (e == 0) *dsum = 0.f;                 // consumed by k_delta (later kernel)
    if (e < E) atomicAdd(&deg[dst[e]], 1);
}

// parallel scan: 49 blocks x 256 thr, 4 elems/thread (1024/block)
__global__ void k_scan_part(const int* __restrict__ deg, int* __restrict__ part, int n) {
    __shared__ int sm[256];
    int b = blockIdx.x, t = threadIdx.x;
    int base = b * 1024 + t * 4;
    int s = 0;
    #pragma unroll
    for (int j = 0; j < 4; j++) if (base + j < n) s += deg[base + j];
    sm[t] = s;
    __syncthreads();
    for (int off = 128; off > 0; off >>= 1) {
        if (t < off) sm[t] += sm[t + off];
        __syncthreads();
    }
    if (t == 0) part[b] = sm[0];
}

__global__ void k_scan_top(const int* __restrict__ part, int* __restrict__ offs,
                           int* __restrict__ row_ptr, int nb, int n) {
    if (threadIdx.x == 0) {
        int acc = 0;
        for (int i = 0; i < nb; i++) { offs[i] = acc; acc += part[i]; }
        row_ptr[n] = acc;
    }
}

__global__ void k_scan_apply(const int* __restrict__ deg, const int* __restrict__ offs,
                             int* __restrict__ row_ptr, int* __restrict__ cursor, int n) {
    __shared__ int sm[256];
    int b = blockIdx.x, t = threadIdx.x;
    int base = b * 1024 + t * 4;
    int v[4]; int s = 0;
    #pragma unroll
    for (int j = 0; j < 4; j++) { v[j] = (base + j < n) ? deg[base + j] : 0; s += v[j]; }
    sm[t] = s;
    __syncthreads();
    for (int off = 1; off < 256; off <<= 1) {
        int y = (t >= off) ? sm[t - off] : 0;
        __syncthreads();
        sm[t] += y;
        __syncthreads();
    }
    int run = offs[b] + sm[t] - s;
    #pragma unroll
    for (int j = 0; j < 4; j++) {
        if (base + j < n) { row_ptr[base + j] = run; cursor[base + j] = run; run += v[j]; }
    }
}

__global__ void k_fill(const int* __restrict__ src, const int* __restrict__ dst,
                       int* __restrict__ cursor, int* __restrict__ csr_src, int E) {
    int e = blockIdx.x * blockDim.x + threadIdx.x;
    if (e < E) {
        int d = dst[e];
        int pos = atomicAdd(&cursor[d], 1);
        csr_src[pos] = src[e];
    }
}

// ---------------- degree scalars ----------------
__global__ void k_delta(const int* __restrict__ deg, float* __restrict__ dsum, int n) {
    int i = blockIdx.x * blockDim.x + threadIdx.x;
    float v = (i < n) ? log1pf((float)deg[i]) : 0.f;
    #pragma unroll
    for (int off = 32; off > 0; off >>= 1) v += __shfl_down(v, off);
    if ((threadIdx.x & 63) == 0) atomicAdd(dsum, v);
}

__global__ void k_scalars(const int* __restrict__ deg, const float* __restrict__ dsum,
                          float* __restrict__ inv_d, float* __restrict__ amp,
                          float* __restrict__ att, int n) {
    int i = blockIdx.x * blockDim.x + threadIdx.x;
    if (i >= n) return;
    float delta = *dsum / (float)n;
    float d = fmaxf((float)deg[i], 1.f);
    float ld = log1pf(d);
    inv_d[i] = 1.f / d;
    amp[i] = ld / delta;
    att[i] = delta / ld;
}

// ---------------- node embedding (fp32 h + bf16 mirror) ----------------
__global__ void k_emb(const float* __restrict__ x, const float* __restrict__ W,
                      const float* __restrict__ b, float* __restrict__ h,
                      unsigned* __restrict__ hb2, int total2) {
    int i = blockIdx.x * blockDim.x + threadIdx.x;
    if (i >= total2) return;
    int node = i >> 6, c = (i & 63) * 2;
    float x0 = x[node * 3 + 0], x1 = x[node * 3 + 1], x2 = x[node * 3 + 2];
    float v0 = x0 * W[c] + x1 * W[DD + c] + x2 * W[2 * DD + c] + b[c];
    float v1 = x0 * W[c + 1] + x1 * W[DD + c + 1] + x2 * W[2 * DD + c + 1] + b[c + 1];
    ((float2*)h)[i] = make_float2(v0, v1);
    hb2[i] = pack_bf2(v0, v1);
}

// ---------------- weight convert: conv_W [L,1536,128] f32 -> Bt [L][3][128][512] bf16 ----
__global__ void k_wconv(const float* __restrict__ W, unsigned short* __restrict__ Bt, int total) {
    int o = blockIdx.x * blockDim.x + threadIdx.x;
    if (o >= total) return;
    int l = o / 196608;
    int r = o % 196608;
    int j = r >> 16;
    int r2 = r & 65535;
    int n = r2 >> 9;
    int k = r2 & 511;
    Bt[o] = f2bf(W[(size_t)l * 196608 + (size_t)(j * 512 + k) * 128 + n]);
}

// ---------------- PNA aggregation (4 nodes/block, wave per node) ----------------
__global__ void k_agg(const unsigned* __restrict__ hb2, const int* __restrict__ row_ptr,
                      const int* __restrict__ csr_src, const float* __restrict__ inv_d,
                      unsigned* __restrict__ aggs_u, float* __restrict__ bn_zero) {
    int tid = threadIdx.x;
    if (blockIdx.x == 0) bn_zero[tid] = 0.f;   // zero bn_sum[128]+bn_sq[128] for next gemm
    int node = blockIdx.x * 4 + (tid >> 6);
    int t = tid & 63;
    int beg = row_ptr[node], end = row_ptr[node + 1];
    float s1a = 0.f, s1b = 0.f, s2a = 0.f, s2b = 0.f;
    float mna = INFINITY, mnb = INFINITY, mxa = -INFINITY, mxb = -INFINITY;
    int e = beg;
    for (; e + 1 < end; e += 2) {             // x2 unroll: 2 independent loads in flight
        int sa = csr_src[e], sb = csr_src[e + 1];
        unsigned va = hb2[(size_t)sa * 64 + t];
        unsigned vb = hb2[(size_t)sb * 64 + t];
        float a0 = bf_lo(va), b0 = bf_hi(va);
        float a1 = bf_lo(vb), b1 = bf_hi(vb);
        s1a += a0 + a1; s2a += a0 * a0 + a1 * a1;
        mna = fminf(mna, fminf(a0, a1)); mxa = fmaxf(mxa, fmaxf(a0, a1));
        s1b += b0 + b1; s2b += b0 * b0 + b1 * b1;
        mnb = fminf(mnb, fminf(b0, b1)); mxb = fmaxf(mxb, fmaxf(b0, b1));
    }
    if (e < end) {
        int sa = csr_src[e];
        unsigned va = hb2[(size_t)sa * 64 + t];
        float a0 = bf_lo(va), b0 = bf_hi(va);
        s1a += a0; s2a += a0 * a0; mna = fminf(mna, a0); mxa = fmaxf(mxa, a0);
        s1b += b0; s2b += b0 * b0; mnb = fminf(mnb, b0); mxb = fmaxf(mxb, b0);
    }
    float id = inv_d[node];
    float meana = s1a * id, meanb = s1b * id;
    float sda = sqrtf(fmaxf(s2a * id - meana * meana, 0.f) + EPSF);
    float sdb = sqrtf(fmaxf(s2b * id - meanb * meanb, 0.f) + EPSF);
    if (beg == end) { mna = 0.f; mxa = 0.f; mnb = 0.f; mxb = 0.f; }
    unsigned* outr = aggs_u + (size_t)node * 256;
    outr[t]       = pack_bf2(meana, meanb);
    outr[64 + t]  = pack_bf2(mna, mnb);
    outr[128 + t] = pack_bf2(mxa, mxb);
    outr[192 + t] = pack_bf2(sda, sdb);
}

// ---------------- MFMA GEMM v4: global_load_lds + XOR swizzle, 128x128 tile ----------------
// A = aggs bf16 [N,512]; Bt = [3][128][512] bf16 (n-major, k contiguous).
// out[r,c] = sum_k A[r,k]*(B0 + amp[r]*B1 + att[r]*B2)[k,c] + bias[c]
// Block: 512 thr (8 waves), tile 128 rows x 128 cols; wave (wrow,wcol) owns
// rows [64*wrow,+64) x cols [32*wcol,+32). LDS rows of 32 shorts = 4 chunks of
// 16B; chunk position p holds global k-chunk p ^ s(row), s = (row ^ row>>2)&3
// -> fragment ds_read_b128 lands 2 lanes/bank-pair (free, m136).
__global__ __launch_bounds__(512, 2) void k_gemm_mfma(
    const unsigned short* __restrict__ A, const unsigned short* __restrict__ Bt,
    const float* __restrict__ bias, const float* __restrict__ amp,
    const float* __restrict__ att, float* __restrict__ outp,
    float* __restrict__ bn_sum, float* __restrict__ bn_sq, int n) {
    __shared__ unsigned short As[128 * 32];
    __shared__ unsigned short Bs[3 * 128 * 32];
    int tid = threadIdx.x;
    int w = tid >> 6, lane = tid & 63;
    int wrow = w >> 2, wcol = w & 3;
    int quad = lane >> 4, l16 = lane & 15;
    int row0 = blockIdx.x * 128;

    f32x4 acc[4][2][3];
    #pragma unroll
    for (int rt = 0; rt < 4; rt++)
        #pragma unroll
        for (int ct = 0; ct < 2; ct++)
            #pragma unroll
            for (int j = 0; j < 3; j++) acc[rt][ct][j] = (f32x4)(0.f);

    // staging: 1 A-chunk + 3 B-chunks of 16B per thread per iter
    int ar = tid >> 2, ac = tid & 3;
    int sA = (ar ^ (ar >> 2)) & 3;
    const unsigned short* gA = A + (size_t)(row0 + ar) * 512 + (ac ^ sA) * 8;
    int aLds = tid * 8;
    const unsigned short* gB[3];
    int bLds[3];
    #pragma unroll
    for (int i = 0; i < 3; i++) {
        int c = i * 512 + tid;
        int br = c >> 2, bc = c & 3;
        int nn = br & 127;
        int sB = (nn ^ (nn >> 2)) & 3;
        gB[i] = Bt + (size_t)br * 512 + (bc ^ sB) * 8;
        bLds[i] = c * 8;
    }
    int a_off[4];
    #pragma unroll
    for (int rt = 0; rt < 4; rt++) {
        int r = wrow * 64 + rt * 16 + l16;
        int s = (r ^ (r >> 2)) & 3;
        a_off[rt] = r * 32 + (quad ^ s) * 8;
    }
    int b_off[2][3];
    #pragma unroll
    for (int ct = 0; ct < 2; ct++) {
        int nn = wcol * 32 + ct * 16 + l16;
        int s = (nn ^ (nn >> 2)) & 3;
        #pragma unroll
        for (int j = 0; j < 3; j++)
            b_off[ct][j] = (j * 128 + nn) * 32 + (quad ^ s) * 8;
    }

    for (int k0 = 0; k0 < 512; k0 += 32) {
        __syncthreads();
        ld16(gA + k0, &As[aLds]);
        #pragma unroll
        for (int i = 0; i < 3; i++) ld16(gB[i] + k0, &Bs[bLds[i]]);
        __syncthreads();
        bf16x8 af[4];
        #pragma unroll
        for (int rt = 0; rt < 4; rt++) af[rt] = *(const bf16x8*)&As[a_off[rt]];
        #pragma unroll
        for (int ct = 0; ct < 2; ct++) {
            #pragma unroll
            for (int j = 0; j < 3; j++) {
                bf16x8 bf = *(const bf16x8*)&Bs[b_off[ct][j]];
                #pragma unroll
                for (int rt = 0; rt < 4; rt++)
                    acc[rt][ct][j] = __builtin_amdgcn_mfma_f32_16x16x32_bf16(
                        af[rt], bf, acc[rt][ct][j], 0, 0, 0);
            }
        }
    }

    // epilogue: combine j via amp/att, bias, write, BN partials
    float psum[2] = {0.f, 0.f}, psq[2] = {0.f, 0.f};
    #pragma unroll
    for (int rt = 0; rt < 4; rt++) {
        #pragma unroll
        for (int reg = 0; reg < 4; reg++) {
            int row = row0 + wrow * 64 + rt * 16 + quad * 4 + reg;
            if (row < n) {
                float am = amp[row], at = att[row];
                #pragma unroll
                for (int ct = 0; ct < 2; ct++) {
                    int col = wcol * 32 + ct * 16 + l16;
                    float v = acc[rt][ct][0][reg] + am * acc[rt][ct][1][reg]
                            + at * acc[rt][ct][2][reg] + bias[col];
                    outp[(size_t)row * DD + col] = v;
                    psum[ct] += v;
                    psq[ct] += v * v;
                }
            }
        }
    }
    #pragma unroll
    for (int ct = 0; ct < 2; ct++) {
        psum[ct] += __shfl_xor(psum[ct], 16, 64);
        psum[ct] += __shfl_xor(psum[ct], 32, 64);
        psq[ct]  += __shfl_xor(psq[ct], 16, 64);
        psq[ct]  += __shfl_xor(psq[ct], 32, 64);
    }
    if (quad == 0) {
        #pragma unroll
        for (int ct = 0; ct < 2; ct++) {
            int col = wcol * 32 + ct * 16 + l16;
            atomicAdd(&bn_sum[col], psum[ct]);
            atomicAdd(&bn_sq[col], psq[ct]);
        }
    }
}

// ---------------- BN stats ----------------
__global__ void k_bnstats(const float* __restrict__ bn_sum, const float* __restrict__ bn_sq,
                          const float* __restrict__ gamma, const float* __restrict__ beta,
                          float* __restrict__ scale, float* __restrict__ shift, int n) {
    int c = threadIdx.x;
    float mu = bn_sum[c] / (float)n;
    float var = bn_sq[c] / (float)n - mu * mu;
    float sc = rsqrtf(var + EPSF) * gamma[c];
    scale[c] = sc;
    shift[c] = beta[c] - mu * sc;
}

// ---------------- BN apply + relu + residual (updates h fp32 + bf16 mirror) --------
__global__ void k_bnapply(const float* __restrict__ outp, const float* __restrict__ scale,
                          const float* __restrict__ shift, float* __restrict__ h,
                          unsigned* __restrict__ hb2, int total2) {
    int i = blockIdx.x * blockDim.x + threadIdx.x;
    if (i >= total2) return;
    int c = (i & 63) * 2;
    float2 o = ((const float2*)outp)[i];
    float v0 = fmaxf(o.x * scale[c] + shift[c], 0.f);
    float v1 = fmaxf(o.y * scale[c + 1] + shift[c + 1], 0.f);
    float2 hh = ((float2*)h)[i];
    hh.x += v0; hh.y += v1;
    ((float2*)h)[i] = hh;
    hb2[i] = pack_bf2(hh.x, hh.y);
}

// ---------------- pool + MLP ----------------
__global__ void k_pool_mlp(const float* __restrict__ h, const int* __restrict__ batch,
                           const float* __restrict__ W1, const float* __restrict__ b1,
                           const float* __restrict__ W2, const float* __restrict__ b2,
                           const float* __restrict__ W3, const float* __restrict__ b3,
                           float* __restrict__ out, int n) {
    __shared__ float gvec[128];
    __shared__ float h1[64];
    __shared__ float h2[32];
    __shared__ int srange[2];
    int g = blockIdx.x;
    int t = threadIdx.x;
    if (t < 2) {
        int target = g + t;
        int lo = 0, hi = n;
        while (lo < hi) {
            int mid = (lo + hi) >> 1;
            if (batch[mid] < target) lo = mid + 1; else hi = mid;
        }
        srange[t] = lo;
    }
    __syncthreads();
    int s = srange[0], e = srange[1];
    float acc = 0.f;
    for (int i = s; i < e; i++) acc += h[(size_t)i * DD + t];
    float cnt = fmaxf((float)(e - s), 1.f);
    gvec[t] = acc / cnt;
    __syncthreads();
    if (t < 64) {
        float a = b1[t];
        for (int k = 0; k < 128; k++) a += gvec[k] * W1[k * 64 + t];
        h1[t] = fmaxf(a, 0.f);
    }
    __syncthreads();
    if (t < 32) {
        float a = b2[t];
        for (int k = 0; k < 64; k++) a += h1[k] * W2[k * 32 + t];
        h2[t] = fmaxf(a, 0.f);
    }
    __syncthreads();
    if (t < 10) {
        float a = b3[t];
        for (int k = 0; k < 32; k++) a += h2[k] * W3[k * 10 + t];
        out[g * NT + t] = a;
    }
}

extern "C" void kernel_launch(void* const* d_in, const int* in_sizes, int n_in,
                              void* d_out, int out_size, void* d_ws, size_t ws_size,
                              hipStream_t stream) {
    const float* x      = (const float*)d_in[0];
    const int*   eidx   = (const int*)d_in[1];
    const int*   batch  = (const int*)d_in[2];
    const float* emb_W  = (const float*)d_in[3];
    const float* emb_b  = (const float*)d_in[4];
    const float* conv_W = (const float*)d_in[5];
    const float* conv_b = (const float*)d_in[6];
    const float* bn_g   = (const float*)d_in[7];
    const float* bn_b   = (const float*)d_in[8];
    const float* W1 = (const float*)d_in[9];
    const float* b1 = (const float*)d_in[10];
    const float* W2 = (const float*)d_in[11];
    const float* b2 = (const float*)d_in[12];
    const float* W3 = (const float*)d_in[13];
    const float* b3 = (const float*)d_in[14];
    float* out = (float*)d_out;

    const int* src = eidx;
    const int* dst = eidx + NE;

    char* p = (char*)d_ws;
    auto carve = [&](size_t bytes) {
        void* r = (void*)p;
        p += (bytes + 255) & ~(size_t)255;
        return r;
    };
    int* deg      = (int*)carve(NN * 4);
    int* row_ptr  = (int*)carve((NN + 1) * 4);
    int* cursor   = (int*)carve(NN * 4);
    int* csr_src  = (int*)carve(NE * 4);
    int* part     = (int*)carve(64 * 4);
    int* offs     = (int*)carve(64 * 4);
    float* inv_d  = (float*)carve(NN * 4);
    float* amp    = (float*)carve(NN * 4);
    float* att    = (float*)carve(NN * 4);
    float* dsum   = (float*)carve(4);
    float* bn_sum = (float*)carve(DD * 4);
    float* bn_sq  = (float*)carve(DD * 4);
    float* scale  = (float*)carve(DD * 4);
    float* shift  = (float*)carve(DD * 4);
    float* h      = (float*)carve((size_t)NN * DD * 4);
    unsigned* hb2 = (unsigned*)carve((size_t)NN * 64 * 4);
    unsigned* aggs_u = (unsigned*)carve((size_t)NN * 256 * 4);   // bf16 [N,512]
    float* outp   = (float*)carve((size_t)NN * DD * 4);          // must follow aggs (OOB pad)
    unsigned short* Bt = (unsigned short*)carve((size_t)NL * 3 * 128 * 512 * 2);

    hipMemsetAsync(deg, 0, NN * 4, stream);

    const int NSB = (NN + 1023) / 1024;   // 49 scan blocks
    k_count<<<(NE + 255) / 256, 256, 0, stream>>>(dst, deg, dsum, NE);
    k_scan_part<<<NSB, 256, 0, stream>>>(deg, part, NN);
    k_scan_top<<<1, 64, 0, stream>>>(part, offs, row_ptr, NSB, NN);
    k_scan_apply<<<NSB, 256, 0, stream>>>(deg, offs, row_ptr, cursor, NN);
    k_fill<<<(NE + 255) / 256, 256, 0, stream>>>(src, dst, cursor, csr_src, NE);
    k_delta<<<(NN + 255) / 256, 256, 0, stream>>>(deg, dsum, NN);
    k_scalars<<<(NN + 255) / 256, 256, 0, stream>>>(deg, dsum, inv_d, amp, att, NN);
    k_emb<<<(NN * 64 + 255) / 256, 256, 0, stream>>>(x, emb_W, emb_b, h, hb2, NN * 64);
    k_wconv<<<(NL * 196608 + 255) / 256, 256, 0, stream>>>(conv_W, Bt, NL * 196608);

    int gemm_blocks = (NN + 127) / 128;   // 391
    for (int l = 0; l < NL; l++) {
        k_agg<<<(NN + 3) / 4, 256, 0, stream>>>(hb2, row_ptr, csr_src, inv_d, aggs_u, bn_sum);
        k_gemm_mfma<<<gemm_blocks, 512, 0, stream>>>(
            (const unsigned short*)aggs_u, Bt + (size_t)l * 3 * 128 * 512,
            conv_b + l * DD, amp, att, outp, bn_sum, bn_sq, NN);
        k_bnstats<<<1, DD, 0, stream>>>(bn_sum, bn_sq, bn_g + l * DD, bn_b + l * DD,
                                        scale, shift, NN);
        k_bnapply<<<(NN * 64 + 255) / 256, 256, 0, stream>>>(outp, scale, shift, h, hb2, NN * 64);
    }

    k_pool_mlp<<<NG, 128, 0, stream>>>(h, batch, W1, b1, W2, b2, W3, b3, out, NN);
}

// Round 5
// 687.507 us; speedup vs baseline: 1.5178x; 1.0027x over previous
//
#include <hip/hip_runtime.h>
#include <math.h>

#define NN 50000
#define NE 600000
#define DD 128
#define NL 4
#define NG 512
#define NT 10
#define EPSF 1e-5f

typedef __bf16 bf16x8 __attribute__((ext_vector_type(8)));
typedef float f32x4 __attribute__((ext_vector_type(4)));

__device__ __forceinline__ unsigned short f2bf(float x) {
    union { float f; unsigned u; } v; v.f = x;
    unsigned r = v.u + 0x7FFFu + ((v.u >> 16) & 1u);
    return (unsigned short)(r >> 16);
}
__device__ __forceinline__ unsigned pack_bf2(float a, float b) {
    return (unsigned)f2bf(a) | ((unsigned)f2bf(b) << 16);
}
__device__ __forceinline__ float bf_lo(unsigned v) {
    union { unsigned u; float f; } w; w.u = (v & 0xFFFFu) << 16; return w.f;
}
__device__ __forceinline__ float bf_hi(unsigned v) {
    union { unsigned u; float f; } w; w.u = v & 0xFFFF0000u; return w.f;
}
__device__ __forceinline__ void ld16(const void* g, void* l) {
    __builtin_amdgcn_global_load_lds(
        (const __attribute__((address_space(1))) unsigned int*)g,
        (__attribute__((address_space(3))) unsigned int*)l, 16, 0, 0);
}

// ---------------- CSR build ----------------
__global__ void k_count(const int* __restrict__ dst, int* __restrict__ deg,
                        float* __restrict__ dsum, int E) {
    int e = blockIdx.x * blockDim.x + threadIdx.x;
    if (e == 0) *dsum = 0.f;                 // consumed by k_delta (later kernel)
    if (e < E) atomicAdd(&deg[dst[e]], 1);
}

// parallel scan: 49 blocks x 256 thr, 4 elems/thread (1024/block)
__global__ void k_scan_part(const int* __restrict__ deg, int* __restrict__ part, int n) {
    __shared__ int sm[256];
    int b = blockIdx.x, t = threadIdx.x;
    int base = b * 1024 + t * 4;
    int s = 0;
    #pragma unroll
    for (int j = 0; j < 4; j++) if (base + j < n) s += deg[base + j];
    sm[t] = s;
    __syncthreads();
    for (int off = 128; off > 0; off >>= 1) {
        if (t < off) sm[t] += sm[t + off];
        __syncthreads();
    }
    if (t == 0) part[b] = sm[0];
}

__global__ void k_scan_top(const int* __restrict__ part, int* __restrict__ offs,
                           int* __restrict__ row_ptr, int nb, int n) {
    if (threadIdx.x == 0) {
        int acc = 0;
        for (int i = 0; i < nb; i++) { offs[i] = acc; acc += part[i]; }
        row_ptr[n] = acc;
    }
}

__global__ void k_scan_apply(const int* __restrict__ deg, const int* __restrict__ offs,
                             int* __restrict__ row_ptr, int* __restrict__ cursor, int n) {
    __shared__ int sm[256];
    int b = blockIdx.x, t = threadIdx.x;
    int base = b * 1024 + t * 4;
    int v[4]; int s = 0;
    #pragma unroll
    for (int j = 0; j < 4; j++) { v[j] = (base + j < n) ? deg[base + j] : 0; s += v[j]; }
    sm[t] = s;
    __syncthreads();
    for (int off = 1; off < 256; off <<= 1) {
        int y = (t >= off) ? sm[t - off] : 0;
        __syncthreads();
        sm[t] += y;
        __syncthreads();
    }
    int run = offs[b] + sm[t] - s;
    #pragma unroll
    for (int j = 0; j < 4; j++) {
        if (base + j < n) { row_ptr[base + j] = run; cursor[base + j] = run; run += v[j]; }
    }
}

__global__ void k_fill(const int* __restrict__ src, const int* __restrict__ dst,
                       int* __restrict__ cursor, int* __restrict__ csr_src, int E) {
    int e = blockIdx.x * blockDim.x + threadIdx.x;
    if (e < E) {
        int d = dst[e];
        int pos = atomicAdd(&cursor[d], 1);
        csr_src[pos] = src[e];
    }
}

// ---------------- degree scalars ----------------
__global__ void k_delta(const int* __restrict__ deg, float* __restrict__ dsum, int n) {
    int i = blockIdx.x * blockDim.x + threadIdx.x;
    float v = (i < n) ? log1pf((float)deg[i]) : 0.f;
    #pragma unroll
    for (int off = 32; off > 0; off >>= 1) v += __shfl_down(v, off);
    if ((threadIdx.x & 63) == 0) atomicAdd(dsum, v);
}

__global__ void k_scalars(const int* __restrict__ deg, const float* __restrict__ dsum,
                          float* __restrict__ inv_d, float* __restrict__ amp,
                          float* __restrict__ att, int n) {
    int i = blockIdx.x * blockDim.x + threadIdx.x;
    if (i >= n) return;
    float delta = *dsum / (float)n;
    float d = fmaxf((float)deg[i], 1.f);
    float ld = log1pf(d);
    inv_d[i] = 1.f / d;
    amp[i] = ld / delta;
    att[i] = delta / ld;
}

// ---------------- node embedding (fp32 h + bf16 mirror) ----------------
__global__ void k_emb(const float* __restrict__ x, const float* __restrict__ W,
                      const float* __restrict__ b, float* __restrict__ h,
                      unsigned* __restrict__ hb2, int total2) {
    int i = blockIdx.x * blockDim.x + threadIdx.x;
    if (i >= total2) return;
    int node = i >> 6, c = (i & 63) * 2;
    float x0 = x[node * 3 + 0], x1 = x[node * 3 + 1], x2 = x[node * 3 + 2];
    float v0 = x0 * W[c] + x1 * W[DD + c] + x2 * W[2 * DD + c] + b[c];
    float v1 = x0 * W[c + 1] + x1 * W[DD + c + 1] + x2 * W[2 * DD + c + 1] + b[c + 1];
    ((float2*)h)[i] = make_float2(v0, v1);
    hb2[i] = pack_bf2(v0, v1);
}

// ---------------- weight convert: conv_W [L,1536,128] f32 -> Bt [L][3][128][512] bf16 ----
__global__ void k_wconv(const float* __restrict__ W, unsigned short* __restrict__ Bt, int total) {
    int o = blockIdx.x * blockDim.x + threadIdx.x;
    if (o >= total) return;
    int l = o / 196608;
    int r = o % 196608;
    int j = r >> 16;
    int r2 = r & 65535;
    int n = r2 >> 9;
    int k = r2 & 511;
    Bt[o] = f2bf(W[(size_t)l * 196608 + (size_t)(j * 512 + k) * 128 + n]);
}

// ---------------- PNA aggregation (4 nodes/block, wave per node) ----------------
__global__ void k_agg(const unsigned* __restrict__ hb2, const int* __restrict__ row_ptr,
                      const int* __restrict__ csr_src, const float* __restrict__ inv_d,
                      unsigned* __restrict__ aggs_u, float* __restrict__ bn_zero) {
    int tid = threadIdx.x;
    if (blockIdx.x == 0) bn_zero[tid] = 0.f;   // zero bn_sum[128]+bn_sq[128] for next gemm
    int node = blockIdx.x * 4 + (tid >> 6);
    int t = tid & 63;
    int beg = row_ptr[node], end = row_ptr[node + 1];
    float s1a = 0.f, s1b = 0.f, s2a = 0.f, s2b = 0.f;
    float mna = INFINITY, mnb = INFINITY, mxa = -INFINITY, mxb = -INFINITY;
    int e = beg;
    for (; e + 1 < end; e += 2) {             // x2 unroll: 2 independent loads in flight
        int sa = csr_src[e], sb = csr_src[e + 1];
        unsigned va = hb2[(size_t)sa * 64 + t];
        unsigned vb = hb2[(size_t)sb * 64 + t];
        float a0 = bf_lo(va), b0 = bf_hi(va);
        float a1 = bf_lo(vb), b1 = bf_hi(vb);
        s1a += a0 + a1; s2a += a0 * a0 + a1 * a1;
        mna = fminf(mna, fminf(a0, a1)); mxa = fmaxf(mxa, fmaxf(a0, a1));
        s1b += b0 + b1; s2b += b0 * b0 + b1 * b1;
        mnb = fminf(mnb, fminf(b0, b1)); mxb = fmaxf(mxb, fmaxf(b0, b1));
    }
    if (e < end) {
        int sa = csr_src[e];
        unsigned va = hb2[(size_t)sa * 64 + t];
        float a0 = bf_lo(va), b0 = bf_hi(va);
        s1a += a0; s2a += a0 * a0; mna = fminf(mna, a0); mxa = fmaxf(mxa, a0);
        s1b += b0; s2b += b0 * b0; mnb = fminf(mnb, b0); mxb = fmaxf(mxb, b0);
    }
    float id = inv_d[node];
    float meana = s1a * id, meanb = s1b * id;
    float sda = sqrtf(fmaxf(s2a * id - meana * meana, 0.f) + EPSF);
    float sdb = sqrtf(fmaxf(s2b * id - meanb * meanb, 0.f) + EPSF);
    if (beg == end) { mna = 0.f; mxa = 0.f; mnb = 0.f; mxb = 0.f; }
    unsigned* outr = aggs_u + (size_t)node * 256;
    outr[t]       = pack_bf2(meana, meanb);
    outr[64 + t]  = pack_bf2(mna, mnb);
    outr[128 + t] = pack_bf2(mxa, mxb);
    outr[192 + t] = pack_bf2(sda, sdb);
}

// ---------------- MFMA GEMM v5: 128x64 tile, 256 thr, 782 blocks (~3/CU) -------------
// A = aggs bf16 [N,512]; Bt = [3][128][512] bf16 (n-major, k contiguous).
// out[r,c] = sum_k A[r,k]*(B0 + amp[r]*B1 + att[r]*B2)[k,c] + bias[c]
// blockIdx.y picks 64-col half. 4 waves: wave w -> rows [64*(w>>1),+64) x cols [32*(w&1),+32).
// Latency hidden by ~3 co-resident blocks/CU (m114 inter-block overlap), not VGPR prefetch
// (round-3 spill) or barrier tricks (m99/m100 neutral).
__global__ __launch_bounds__(256, 3) void k_gemm_mfma(
    const unsigned short* __restrict__ A, const unsigned short* __restrict__ Bt,
    const float* __restrict__ bias, const float* __restrict__ amp,
    const float* __restrict__ att, float* __restrict__ outp,
    float* __restrict__ bn_sum, float* __restrict__ bn_sq, int n) {
    __shared__ unsigned short As[128 * 32];
    __shared__ unsigned short Bs[3 * 64 * 32];
    int tid = threadIdx.x;
    int w = tid >> 6, lane = tid & 63;
    int wrow = w >> 1, wcol = w & 1;
    int quad = lane >> 4, l16 = lane & 15;
    int row0 = blockIdx.x * 128;
    int c0 = blockIdx.y * 64;

    f32x4 acc[4][2][3];
    #pragma unroll
    for (int rt = 0; rt < 4; rt++)
        #pragma unroll
        for (int ct = 0; ct < 2; ct++)
            #pragma unroll
            for (int j = 0; j < 3; j++) acc[rt][ct][j] = (f32x4)(0.f);

    // staging: 2 A-chunks + 3 B-chunks of 16B per thread per iter
    const unsigned short* gA[2];
    int aLds[2];
    #pragma unroll
    for (int i = 0; i < 2; i++) {
        int c = i * 256 + tid;
        int row = c >> 2, kc = c & 3;
        gA[i] = A + (size_t)(row0 + row) * 512 + kc * 8;
        aLds[i] = c * 8;
    }
    const unsigned short* gB[3];
    int bLds[3];
    int bn_ = tid >> 2, bk = tid & 3;
    #pragma unroll
    for (int i = 0; i < 3; i++) {
        gB[i] = Bt + (size_t)(i * 128 + c0 + bn_) * 512 + bk * 8;
        bLds[i] = (i * 64 + bn_) * 32 + bk * 8;
    }
    int a_off[4];
    #pragma unroll
    for (int rt = 0; rt < 4; rt++)
        a_off[rt] = (wrow * 64 + rt * 16 + l16) * 32 + quad * 8;
    int b_off[2][3];
    #pragma unroll
    for (int ct = 0; ct < 2; ct++)
        #pragma unroll
        for (int j = 0; j < 3; j++)
            b_off[ct][j] = (j * 64 + wcol * 32 + ct * 16 + l16) * 32 + quad * 8;

    for (int k0 = 0; k0 < 512; k0 += 32) {
        __syncthreads();
        ld16(gA[0] + k0, &As[aLds[0]]);
        ld16(gA[1] + k0, &As[aLds[1]]);
        #pragma unroll
        for (int i = 0; i < 3; i++) ld16(gB[i] + k0, &Bs[bLds[i]]);
        __syncthreads();
        bf16x8 af[4];
        #pragma unroll
        for (int rt = 0; rt < 4; rt++) af[rt] = *(const bf16x8*)&As[a_off[rt]];
        #pragma unroll
        for (int ct = 0; ct < 2; ct++) {
            #pragma unroll
            for (int j = 0; j < 3; j++) {
                bf16x8 bf = *(const bf16x8*)&Bs[b_off[ct][j]];
                #pragma unroll
                for (int rt = 0; rt < 4; rt++)
                    acc[rt][ct][j] = __builtin_amdgcn_mfma_f32_16x16x32_bf16(
                        af[rt], bf, acc[rt][ct][j], 0, 0, 0);
            }
        }
    }

    // epilogue: combine j via amp/att, bias, write, BN partials
    float psum[2] = {0.f, 0.f}, psq[2] = {0.f, 0.f};
    #pragma unroll
    for (int rt = 0; rt < 4; rt++) {
        #pragma unroll
        for (int reg = 0; reg < 4; reg++) {
            int row = row0 + wrow * 64 + rt * 16 + quad * 4 + reg;
            if (row < n) {
                float am = amp[row], at = att[row];
                #pragma unroll
                for (int ct = 0; ct < 2; ct++) {
                    int col = c0 + wcol * 32 + ct * 16 + l16;
                    float v = acc[rt][ct][0][reg] + am * acc[rt][ct][1][reg]
                            + at * acc[rt][ct][2][reg] + bias[col];
                    outp[(size_t)row * DD + col] = v;
                    psum[ct] += v;
                    psq[ct] += v * v;
                }
            }
        }
    }
    #pragma unroll
    for (int ct = 0; ct < 2; ct++) {
        psum[ct] += __shfl_xor(psum[ct], 16, 64);
        psum[ct] += __shfl_xor(psum[ct], 32, 64);
        psq[ct]  += __shfl_xor(psq[ct], 16, 64);
        psq[ct]  += __shfl_xor(psq[ct], 32, 64);
    }
    if (quad == 0) {
        #pragma unroll
        for (int ct = 0; ct < 2; ct++) {
            int col = c0 + wcol * 32 + ct * 16 + l16;
            atomicAdd(&bn_sum[col], psum[ct]);
            atomicAdd(&bn_sq[col], psq[ct]);
        }
    }
}

// ---------------- BN stats+apply+relu+residual (fused; updates h fp32 + bf16 mirror) ----
__global__ void k_bnapply(const float* __restrict__ outp, const float* __restrict__ bn_sum,
                          const float* __restrict__ bn_sq, const float* __restrict__ gamma,
                          const float* __restrict__ beta, float* __restrict__ h,
                          unsigned* __restrict__ hb2, int total4) {
    int i = blockIdx.x * blockDim.x + threadIdx.x;
    if (i >= total4) return;
    int c = (i & 31) * 4;
    const float invn = 1.f / (float)NN;
    float4 o = ((const float4*)outp)[i];
    float4 hh = ((float4*)h)[i];
    float oo[4] = {o.x, o.y, o.z, o.w};
    float hs[4] = {hh.x, hh.y, hh.z, hh.w};
    #pragma unroll
    for (int j = 0; j < 4; j++) {
        float mu = bn_sum[c + j] * invn;
        float var = bn_sq[c + j] * invn - mu * mu;
        float sc = rsqrtf(var + EPSF) * gamma[c + j];
        float sh = beta[c + j] - mu * sc;
        hs[j] += fmaxf(oo[j] * sc + sh, 0.f);
    }
    ((float4*)h)[i] = make_float4(hs[0], hs[1], hs[2], hs[3]);
    hb2[i * 2]     = pack_bf2(hs[0], hs[1]);
    hb2[i * 2 + 1] = pack_bf2(hs[2], hs[3]);
}

// ---------------- pool + MLP ----------------
__global__ void k_pool_mlp(const float* __restrict__ h, const int* __restrict__ batch,
                           const float* __restrict__ W1, const float* __restrict__ b1,
                           const float* __restrict__ W2, const float* __restrict__ b2,
                           const float* __restrict__ W3, const float* __restrict__ b3,
                           float* __restrict__ out, int n) {
    __shared__ float gvec[128];
    __shared__ float h1[64];
    __shared__ float h2[32];
    __shared__ int srange[2];
    int g = blockIdx.x;
    int t = threadIdx.x;
    if (t < 2) {
        int target = g + t;
        int lo = 0, hi = n;
        while (lo < hi) {
            int mid = (lo + hi) >> 1;
            if (batch[mid] < target) lo = mid + 1; else hi = mid;
        }
        srange[t] = lo;
    }
    __syncthreads();
    int s = srange[0], e = srange[1];
    float acc = 0.f;
    for (int i = s; i < e; i++) acc += h[(size_t)i * DD + t];
    float cnt = fmaxf((float)(e - s), 1.f);
    gvec[t] = acc / cnt;
    __syncthreads();
    if (t < 64) {
        float a = b1[t];
        for (int k = 0; k < 128; k++) a += gvec[k] * W1[k * 64 + t];
        h1[t] = fmaxf(a, 0.f);
    }
    __syncthreads();
    if (t < 32) {
        float a = b2[t];
        for (int k = 0; k < 64; k++) a += h1[k] * W2[k * 32 + t];
        h2[t] = fmaxf(a, 0.f);
    }
    __syncthreads();
    if (t < 10) {
        float a = b3[t];
        for (int k = 0; k < 32; k++) a += h2[k] * W3[k * 10 + t];
        out[g * NT + t] = a;
    }
}

extern "C" void kernel_launch(void* const* d_in, const int* in_sizes, int n_in,
                              void* d_out, int out_size, void* d_ws, size_t ws_size,
                              hipStream_t stream) {
    const float* x      = (const float*)d_in[0];
    const int*   eidx   = (const int*)d_in[1];
    const int*   batch  = (const int*)d_in[2];
    const float* emb_W  = (const float*)d_in[3];
    const float* emb_b  = (const float*)d_in[4];
    const float* conv_W = (const float*)d_in[5];
    const float* conv_b = (const float*)d_in[6];
    const float* bn_g   = (const float*)d_in[7];
    const float* bn_b   = (const float*)d_in[8];
    const float* W1 = (const float*)d_in[9];
    const float* b1 = (const float*)d_in[10];
    const float* W2 = (const float*)d_in[11];
    const float* b2 = (const float*)d_in[12];
    const float* W3 = (const float*)d_in[13];
    const float* b3 = (const float*)d_in[14];
    float* out = (float*)d_out;

    const int* src = eidx;
    const int* dst = eidx + NE;

    char* p = (char*)d_ws;
    auto carve = [&](size_t bytes) {
        void* r = (void*)p;
        p += (bytes + 255) & ~(size_t)255;
        return r;
    };
    int* deg      = (int*)carve(NN * 4);
    int* row_ptr  = (int*)carve((NN + 1) * 4);
    int* cursor   = (int*)carve(NN * 4);
    int* csr_src  = (int*)carve(NE * 4);
    int* part     = (int*)carve(64 * 4);
    int* offs     = (int*)carve(64 * 4);
    float* inv_d  = (float*)carve(NN * 4);
    float* amp    = (float*)carve(NN * 4);
    float* att    = (float*)carve(NN * 4);
    float* dsum   = (float*)carve(4);
    float* bn_sum = (float*)carve(DD * 4);
    float* bn_sq  = (float*)carve(DD * 4);
    float* h      = (float*)carve((size_t)NN * DD * 4);
    unsigned* hb2 = (unsigned*)carve((size_t)NN * 64 * 4);
    unsigned* aggs_u = (unsigned*)carve((size_t)NN * 256 * 4);   // bf16 [N,512]
    float* outp   = (float*)carve((size_t)NN * DD * 4);          // must follow aggs (OOB pad)
    unsigned short* Bt = (unsigned short*)carve((size_t)NL * 3 * 128 * 512 * 2);

    hipMemsetAsync(deg, 0, NN * 4, stream);

    const int NSB = (NN + 1023) / 1024;   // 49 scan blocks
    k_count<<<(NE + 255) / 256, 256, 0, stream>>>(dst, deg, dsum, NE);
    k_scan_part<<<NSB, 256, 0, stream>>>(deg, part, NN);
    k_scan_top<<<1, 64, 0, stream>>>(part, offs, row_ptr, NSB, NN);
    k_scan_apply<<<NSB, 256, 0, stream>>>(deg, offs, row_ptr, cursor, NN);
    k_fill<<<(NE + 255) / 256, 256, 0, stream>>>(src, dst, cursor, csr_src, NE);
    k_delta<<<(NN + 255) / 256, 256, 0, stream>>>(deg, dsum, NN);
    k_scalars<<<(NN + 255) / 256, 256, 0, stream>>>(deg, dsum, inv_d, amp, att, NN);
    k_emb<<<(NN * 64 + 255) / 256, 256, 0, stream>>>(x, emb_W, emb_b, h, hb2, NN * 64);
    k_wconv<<<(NL * 196608 + 255) / 256, 256, 0, stream>>>(conv_W, Bt, NL * 196608);

    dim3 gemm_grid((NN + 127) / 128, 2);   // 391 x 2 = 782 blocks (~3/CU)
    for (int l = 0; l < NL; l++) {
        k_agg<<<(NN + 3) / 4, 256, 0, stream>>>(hb2, row_ptr, csr_src, inv_d, aggs_u, bn_sum);
        k_gemm_mfma<<<gemm_grid, 256, 0, stream>>>(
            (const unsigned short*)aggs_u, Bt + (size_t)l * 3 * 128 * 512,
            conv_b + l * DD, amp, att, outp, bn_sum, bn_sq, NN);
        k_bnapply<<<(NN * 32 + 255) / 256, 256, 0, stream>>>(
            outp, bn_sum, bn_sq, bn_g + l * DD, bn_b + l * DD, h, hb2, NN * 32);
    }

    k_pool_mlp<<<NG, 128, 0, stream>>>(h, batch, W1, b1, W2, b2, W3, b3, out, NN);
}